// Round 1
// baseline (648.065 us; speedup 1.0000x reference)
//
#include <hip/hip_runtime.h>
#include <stdint.h>
#include <stddef.h>

#define BATCH 512
#define NQ    65536
#define DIM   768
#define DIM2  1536

typedef __attribute__((ext_vector_type(4))) float f32x4;
typedef __attribute__((ext_vector_type(8))) unsigned short u16x8;
typedef __attribute__((ext_vector_type(8))) __bf16 bf16x8;

// ---------- fp32 <-> bf16 (round-to-nearest-even) ----------
static __device__ __forceinline__ unsigned short f2bf(float x){
    unsigned int u = __float_as_uint(x);
    unsigned int r = ((u >> 16) & 1u) + 0x7fffu;
    return (unsigned short)((u + r) >> 16);
}
static __device__ __forceinline__ float bf2f(unsigned short h){
    return __uint_as_float(((unsigned int)h) << 16);
}

// ---------- top-2 tracking ----------
struct T2 { float v1, v2; int i1, i2; };
static __device__ __forceinline__ void t2_add(T2& t, float v, int i){
    if (v > t.v1 || (v == t.v1 && i < t.i1)) { t.v2 = t.v1; t.i2 = t.i1; t.v1 = v; t.i1 = i; }
    else if (v > t.v2 || (v == t.v2 && i < t.i2)) { t.v2 = v; t.i2 = i; }
}
static __device__ __forceinline__ T2 t2_init(){ T2 t; t.v1 = -3.4e38f; t.v2 = -3.4e38f; t.i1 = 0x7fffffff; t.i2 = 0x7fffffff; return t; }

// ---------- prep: L2-normalize features, split to bf16 hi/lo, seed queue rows ----------
__global__ __launch_bounds__(256) void prep_kernel(
    const float* __restrict__ img, const float* __restrict__ txt,
    float* __restrict__ img_f, float* __restrict__ txt_f,
    unsigned short* __restrict__ X2hi, unsigned short* __restrict__ X2lo,
    unsigned short* __restrict__ X1hi, unsigned short* __restrict__ X1lo,
    float* __restrict__ out2, float* __restrict__ out3)
{
    int b = blockIdx.x;
    bool isimg = (b < BATCH);
    int row = isimg ? b : b - BATCH;
    const float* src = (isimg ? img : txt) + (size_t)row * DIM;
    float v[3];
    float ss = 0.f;
    #pragma unroll
    for (int i = 0; i < 3; i++){ v[i] = src[threadIdx.x + i*256]; ss += v[i]*v[i]; }
    #pragma unroll
    for (int m = 1; m < 64; m <<= 1) ss += __shfl_xor(ss, m);
    __shared__ float red[4];
    if ((threadIdx.x & 63) == 0) red[threadIdx.x >> 6] = ss;
    __syncthreads();
    float tot = red[0] + red[1] + red[2] + red[3];
    float scale = 1.0f / fmaxf(sqrtf(tot), 1e-12f);
    float* fdst = (isimg ? img_f : txt_f) + (size_t)row * DIM;
    float* odst = (isimg ? out2  : out3 ) + (size_t)row * DIM;
    unsigned short* hid = (isimg ? X2hi : X1hi) + (size_t)row * DIM2;
    unsigned short* lod = (isimg ? X2lo : X1lo) + (size_t)row * DIM2;
    #pragma unroll
    for (int i = 0; i < 3; i++){
        int c = threadIdx.x + i*256;
        float y = v[i] * scale;
        fdst[c] = y; odst[c] = y;
        unsigned short h = f2bf(y);
        hid[c] = h; lod[c] = f2bf(y - bf2f(h));
    }
}

// ---------- transpose W [1536][768] -> Wt [768][1536] (fp32) ----------
__global__ __launch_bounds__(256) void transpose_kernel(
    const float* __restrict__ Wd, const float* __restrict__ Wc,
    float* __restrict__ Td, float* __restrict__ Tc)
{
    __shared__ float t[32][33];
    const float* W = blockIdx.z ? Wc : Wd;
    float*       T = blockIdx.z ? Tc : Td;
    int x0 = blockIdx.x * 32;          // col of W
    int y0 = blockIdx.y * 32;          // row of W
    int tx = threadIdx.x & 31, ty = threadIdx.x >> 5;
    #pragma unroll
    for (int i = 0; i < 32; i += 8)
        t[ty + i][tx] = W[(size_t)(y0 + ty + i) * DIM + x0 + tx];
    __syncthreads();
    #pragma unroll
    for (int i = 0; i < 32; i += 8)
        T[(size_t)(x0 + ty + i) * DIM2 + y0 + tx] = t[tx][ty + i];
}

// ---------- GEMM: C = A * B^T, A = bf16 hi/lo pair [M][lda], B = fp32 [N][ldb] ----------
#define EPI_TOP2      0
#define EPI_BIAS_RELU 1
#define EPI_BIAS      2
#define EPI_SCALE     3

template<int BM,int BN,int WGM,int WGN,int NTERMS,int EPI,bool WT>
__global__ __launch_bounds__(WGM*WGN*64) void gemm_kernel(
    const unsigned short* __restrict__ Ahi, const unsigned short* __restrict__ Alo, int lda,
    const float* __restrict__ B, int ldb, int K, int N,
    float* __restrict__ wt_out,
    const float* __restrict__ bias,
    float* __restrict__ outp,
    unsigned short* __restrict__ dsthi, unsigned short* __restrict__ dstlo, int ldd, int dstoff,
    const float* __restrict__ scale_ptr, int Mtot)
{
    constexpr int WM = BM / WGM, WN = BN / WGN;
    constexpr int MF = WM / 16, NF = WN / 16;
    constexpr int NT = WGM * WGN * 64;
    constexpr int ABYTES = BM * 128;   // per row: 64 bf16 = [hi 32 | lo 32], 8 granules of 16B
    constexpr int BBYTES = BN * 128;
    constexpr int BUF = ABYTES + BBYTES;
    static_assert(BN * 4 == NT, "B staging: one row per 4 threads");
    static_assert((BM * 8) % NT == 0, "A staging rounds integral");

    __shared__ __align__(16) char lds[2 * BUF];

    const int tid  = threadIdx.x;
    const int wid  = tid >> 6, lane = tid & 63;
    const int wm   = wid / WGN, wn = wid % WGN;
    const int lr   = lane & 15, lg = lane >> 4;
    const int nb   = blockIdx.x, mb = blockIdx.y;
    const int m0   = mb * BM, n0 = nb * BN;

    f32x4 acc[MF][NF] = {};
    f32x4 breg0, breg1;

    auto stageA = [&](int buf, int k0){
        char* base = lds + buf * BUF;
        constexpr int RA = BM * 8 / NT;
        #pragma unroll
        for (int r = 0; r < RA; r++){
            int G = r * NT + tid;
            int row = G >> 3, slot = G & 7;
            int s0 = slot ^ (row & 7);                        // pre-swizzled source granule
            const unsigned short* src = ((s0 < 4) ? Ahi : Alo)
                + (size_t)(m0 + row) * lda + (k0 + (s0 & 3) * 8);
            char* ldst = base + r * NT * 16 + (tid & ~63) * 16;  // wave-uniform base
            __builtin_amdgcn_global_load_lds(
                (const __attribute__((address_space(1))) void*)src,
                (__attribute__((address_space(3))) void*)ldst, 16, 0, 0);
        }
    };
    auto loadB = [&](int kt){
        int k0 = kt * 32;
        int row = tid >> 2, quad = tid & 3;
        const float* bp = B + (size_t)(n0 + row) * ldb + k0 + quad * 8;
        breg0 = *(const f32x4*)bp;
        breg1 = *(const f32x4*)(bp + 4);
        if (WT && mb == 0 && (n0 + row) >= BATCH){
            float* wp = wt_out + (size_t)(n0 + row) * ldb + k0 + quad * 8;
            *(f32x4*)wp = breg0; *(f32x4*)(wp + 4) = breg1;
        }
    };
    auto writeB = [&](int buf){
        char* base = lds + buf * BUF + ABYTES;
        int row = tid >> 2, quad = tid & 3;
        u16x8 h8, l8;
        #pragma unroll
        for (int j = 0; j < 8; j++){
            float x = (j < 4) ? breg0[j] : breg1[j - 4];
            unsigned short h = f2bf(x);
            h8[j] = h; l8[j] = f2bf(x - bf2f(h));
        }
        int sh = quad ^ (row & 7), sl = (4 + quad) ^ (row & 7);
        *(u16x8*)(base + row * 128 + sh * 16) = h8;
        *(u16x8*)(base + row * 128 + sl * 16) = l8;
    };
    auto compute = [&](int buf){
        const char* Ab = lds + buf * BUF;
        const char* Bb = Ab + ABYTES;
        bf16x8 ah[MF], al[MF], bh[NF], bl[NF];
        #pragma unroll
        for (int mf = 0; mf < MF; mf++){
            int row = wm * WM + mf * 16 + lr;
            const char* rp = Ab + row * 128;
            ah[mf] = *(const bf16x8*)(rp + ((lg ^ (row & 7)) << 4));
            if (NTERMS > 1) al[mf] = *(const bf16x8*)(rp + (((4 + lg) ^ (row & 7)) << 4));
        }
        #pragma unroll
        for (int nf = 0; nf < NF; nf++){
            int row = wn * WN + nf * 16 + lr;
            const char* rp = Bb + row * 128;
            bh[nf] = *(const bf16x8*)(rp + ((lg ^ (row & 7)) << 4));
            if (NTERMS > 2) bl[nf] = *(const bf16x8*)(rp + (((4 + lg) ^ (row & 7)) << 4));
        }
        #pragma unroll
        for (int mf = 0; mf < MF; mf++)
        #pragma unroll
        for (int nf = 0; nf < NF; nf++){
            acc[mf][nf] = __builtin_amdgcn_mfma_f32_16x16x32_bf16(ah[mf], bh[nf], acc[mf][nf], 0, 0, 0);
            if (NTERMS > 1) acc[mf][nf] = __builtin_amdgcn_mfma_f32_16x16x32_bf16(al[mf], bh[nf], acc[mf][nf], 0, 0, 0);
            if (NTERMS > 2) acc[mf][nf] = __builtin_amdgcn_mfma_f32_16x16x32_bf16(ah[mf], bl[nf], acc[mf][nf], 0, 0, 0);
        }
    };

    stageA(0, 0); loadB(0); writeB(0);
    __syncthreads();
    const int nk = K / 32;
    int cur = 0;
    for (int kt = 0; kt < nk; kt++){
        if (kt + 1 < nk){ stageA(cur ^ 1, (kt + 1) * 32); loadB(kt + 1); }
        compute(cur);
        if (kt + 1 < nk){ writeB(cur ^ 1); }
        __syncthreads();
        cur ^= 1;
    }

    // ---------- epilogues ----------
    if constexpr (EPI == EPI_TOP2){
        T2* t2l = (T2*)lds;   // [WGN][BM]
        #pragma unroll
        for (int mf = 0; mf < MF; mf++){
            #pragma unroll
            for (int r = 0; r < 4; r++){
                T2 t = t2_init();
                #pragma unroll
                for (int nf = 0; nf < NF; nf++){
                    int gc = n0 + wn * WN + nf * 16 + lr;
                    t2_add(t, acc[mf][nf][r], gc);
                }
                #pragma unroll
                for (int m = 1; m < 16; m <<= 1){
                    float ov1 = __shfl_xor(t.v1, m), ov2 = __shfl_xor(t.v2, m);
                    int   oi1 = __shfl_xor(t.i1, m), oi2 = __shfl_xor(t.i2, m);
                    t2_add(t, ov1, oi1); t2_add(t, ov2, oi2);
                }
                if (lr == 0){
                    int rowit = wm * WM + mf * 16 + lg * 4 + r;
                    t2l[wn * BM + rowit] = t;
                }
            }
        }
        __syncthreads();
        if (tid < BM){
            T2 t = t2l[tid];
            #pragma unroll
            for (int w = 1; w < WGN; w++){
                T2 o = t2l[w * BM + tid];
                t2_add(t, o.v1, o.i1); t2_add(t, o.v2, o.i2);
            }
            f32x4 pk; pk[0] = t.v1; pk[1] = __int_as_float(t.i1); pk[2] = t.v2; pk[3] = __int_as_float(t.i2);
            ((f32x4*)outp)[(size_t)nb * Mtot + (m0 + tid)] = pk;
        }
    } else if constexpr (EPI == EPI_SCALE){
        float sc = scale_ptr[0];
        #pragma unroll
        for (int mf = 0; mf < MF; mf++)
        #pragma unroll
        for (int nf = 0; nf < NF; nf++)
        #pragma unroll
        for (int r = 0; r < 4; r++){
            int grow = m0 + wm * WM + mf * 16 + lg * 4 + r;
            int gcol = n0 + wn * WN + nf * 16 + lr;
            outp[(size_t)grow * N + gcol] = acc[mf][nf][r] * sc;
        }
    } else {
        #pragma unroll
        for (int mf = 0; mf < MF; mf++)
        #pragma unroll
        for (int nf = 0; nf < NF; nf++)
        #pragma unroll
        for (int r = 0; r < 4; r++){
            int grow = m0 + wm * WM + mf * 16 + lg * 4 + r;
            int gcol = n0 + wn * WN + nf * 16 + lr;
            float c = acc[mf][nf][r] + bias[gcol];
            if (EPI == EPI_BIAS_RELU) c = fmaxf(c, 0.f);
            unsigned short h = f2bf(c);
            size_t o = (size_t)grow * ldd + dstoff + gcol;
            dsthi[o] = h;
            dstlo[o] = f2bf(c - bf2f(h));
        }
    }
}

// ---------- phase B: global top-2 merge + exact fp32 rescore -> argmax index ----------
__global__ __launch_bounds__(64) void phaseB_kernel(
    const f32x4* __restrict__ top2ws, int ntiles,
    const float* __restrict__ img_f, const float* __restrict__ qtxt,
    float* __restrict__ out_ind, int* __restrict__ ws_ind)
{
    int row = blockIdx.x;
    int lane = threadIdx.x;
    T2 t = t2_init();
    for (int j = lane; j < ntiles; j += 64){
        f32x4 e = top2ws[(size_t)j * BATCH + row];
        t2_add(t, e[0], __float_as_int(e[1]));
        t2_add(t, e[2], __float_as_int(e[3]));
    }
    #pragma unroll
    for (int m = 1; m < 64; m <<= 1){
        float ov1 = __shfl_xor(t.v1, m), ov2 = __shfl_xor(t.v2, m);
        int   oi1 = __shfl_xor(t.i1, m), oi2 = __shfl_xor(t.i2, m);
        t2_add(t, ov1, oi1); t2_add(t, ov2, oi2);
    }
    // exact fp32 rescore of the two candidates
    const float* a  = img_f + (size_t)row * DIM;
    const float* b1 = qtxt + (size_t)t.i1 * DIM;
    const float* b2 = qtxt + (size_t)t.i2 * DIM;
    float s1 = 0.f, s2 = 0.f;
    for (int c = lane; c < DIM; c += 64){ float av = a[c]; s1 += av * b1[c]; s2 += av * b2[c]; }
    #pragma unroll
    for (int m = 1; m < 64; m <<= 1){ s1 += __shfl_xor(s1, m); s2 += __shfl_xor(s2, m); }
    int ind = (s2 > s1 || (s2 == s1 && t.i2 < t.i1)) ? t.i2 : t.i1;
    if (lane == 0){ out_ind[row] = (float)ind; ws_ind[row] = ind; }
}

// ---------- gather t_similar rows into X1[:, 768:1536] as bf16 hi/lo ----------
__global__ __launch_bounds__(256) void gather_kernel(
    const int* __restrict__ ws_ind, const float* __restrict__ qtxt,
    unsigned short* __restrict__ X1hi, unsigned short* __restrict__ X1lo)
{
    int row = blockIdx.x;
    int ind = ws_ind[row];
    const float* src = qtxt + (size_t)ind * DIM;
    for (int c = threadIdx.x; c < DIM; c += 256){
        float x = src[c];
        unsigned short h = f2bf(x);
        X1hi[(size_t)row * DIM2 + DIM + c] = h;
        X1lo[(size_t)row * DIM2 + DIM + c] = f2bf(x - bf2f(h));
    }
}

extern "C" void kernel_launch(void* const* d_in, const int* in_sizes, int n_in,
                              void* d_out, int out_size, void* d_ws, size_t ws_size,
                              hipStream_t stream)
{
    (void)in_sizes; (void)n_in; (void)out_size; (void)ws_size;
    const float* img  = (const float*)d_in[0];
    const float* txt  = (const float*)d_in[1];
    const float* qimg = (const float*)d_in[2];
    const float* qtxt = (const float*)d_in[3];
    const float* Wd   = (const float*)d_in[4];
    const float* bd   = (const float*)d_in[5];
    const float* Wc   = (const float*)d_in[6];
    const float* bc   = (const float*)d_in[7];
    const float* ls   = (const float*)d_in[8];

    float* out0 = (float*)d_out;                    // logits [512][65536]
    float* out1 = out0 + (size_t)BATCH * NQ;        // ind_similar [512] (as f32)
    float* out2 = out1 + BATCH;                     // new_queue_img [65536][768]
    float* out3 = out2 + (size_t)NQ * DIM;          // new_queue_txt [65536][768]

    char* w = (char*)d_ws;
    auto alloc = [&](size_t bytes){ char* p = w; w += (bytes + 255) & ~(size_t)255; return p; };
    unsigned short* X1hi  = (unsigned short*)alloc((size_t)BATCH * DIM2 * 2);
    unsigned short* X1lo  = (unsigned short*)alloc((size_t)BATCH * DIM2 * 2);
    unsigned short* X2hi  = (unsigned short*)alloc((size_t)BATCH * DIM2 * 2);
    unsigned short* X2lo  = (unsigned short*)alloc((size_t)BATCH * DIM2 * 2);
    unsigned short* combhi= (unsigned short*)alloc((size_t)BATCH * DIM * 2);
    unsigned short* comblo= (unsigned short*)alloc((size_t)BATCH * DIM * 2);
    float* img_f  = (float*)alloc((size_t)BATCH * DIM * 4);
    float* txt_f  = (float*)alloc((size_t)BATCH * DIM * 4);
    float* Td     = (float*)alloc((size_t)DIM * DIM2 * 4);
    float* Tc     = (float*)alloc((size_t)DIM * DIM2 * 4);
    float* top2ws = (float*)alloc((size_t)(NQ / 128) * BATCH * 16);
    int*   ws_ind = (int*)alloc(BATCH * 4);

    // 1) normalize features, split, seed queue rows 0..511 of outputs
    prep_kernel<<<dim3(2 * BATCH), dim3(256), 0, stream>>>(
        img, txt, img_f, txt_f, X2hi, X2lo, X1hi, X1lo, out2, out3);

    // 2) transpose weights to [768][1536] fp32
    transpose_kernel<<<dim3(DIM / 32, DIM2 / 32, 2), dim3(256), 0, stream>>>(Wd, Wc, Td, Tc);

    // 3) retrieval GEMM (split-bf16, 3 terms) + per-tile top2 + queue_txt write-through
    gemm_kernel<256,128,4,2,3,EPI_TOP2,true><<<dim3(NQ / 128, 2), dim3(512), 0, stream>>>(
        X2hi, X2lo, DIM2, qtxt, DIM, DIM, NQ,
        out3, nullptr, top2ws, nullptr, nullptr, 0, 0, nullptr, BATCH);

    // 4) global top-2 + exact rescore -> ind_similar
    phaseB_kernel<<<dim3(BATCH), dim3(64), 0, stream>>>(
        (const f32x4*)top2ws, NQ / 128, img_f, qtxt, out1, ws_ind);

    // 5) gather t_similar into X1[:, 768:]
    gather_kernel<<<dim3(BATCH), dim3(256), 0, stream>>>(ws_ind, qtxt, X1hi, X1lo);

    // 6) diff = relu(X1 @ W_diff + b_diff) -> X2[:, 768:] (split)
    gemm_kernel<64,64,2,2,3,EPI_BIAS_RELU,false><<<dim3(DIM / 64, BATCH / 64), dim3(256), 0, stream>>>(
        X1hi, X1lo, DIM2, Td, DIM2, DIM2, DIM,
        nullptr, bd, nullptr, X2hi, X2lo, DIM2, DIM, nullptr, BATCH);

    // 7) combined = X2 @ W_comb + b_comb -> comb hi/lo
    gemm_kernel<64,64,2,2,3,EPI_BIAS,false><<<dim3(DIM / 64, BATCH / 64), dim3(256), 0, stream>>>(
        X2hi, X2lo, DIM2, Tc, DIM2, DIM2, DIM,
        nullptr, bc, nullptr, combhi, comblo, DIM, 0, nullptr, BATCH);

    // 8) logits = scale * combined @ queue_img^T + queue_img write-through
    gemm_kernel<256,128,4,2,1,EPI_SCALE,true><<<dim3(NQ / 128, 2), dim3(512), 0, stream>>>(
        combhi, comblo, DIM, qimg, DIM, DIM, NQ,
        out2, nullptr, out0, nullptr, nullptr, 0, 0, ls, BATCH);
}

// Round 2
// 579.299 us; speedup vs baseline: 1.1187x; 1.1187x over previous
//
#include <hip/hip_runtime.h>
#include <stdint.h>
#include <stddef.h>

#define BATCH 512
#define NQ    65536
#define DIM   768
#define DIM2  1536

typedef __attribute__((ext_vector_type(4))) float f32x4;
typedef __attribute__((ext_vector_type(4))) unsigned short u16x4;
typedef __attribute__((ext_vector_type(8))) unsigned short u16x8;
typedef __attribute__((ext_vector_type(8))) __bf16 bf16x8;

// ---------- fp32 <-> bf16 (round-to-nearest-even) ----------
static __device__ __forceinline__ unsigned short f2bf(float x){
    unsigned int u = __float_as_uint(x);
    unsigned int r = ((u >> 16) & 1u) + 0x7fffu;
    return (unsigned short)((u + r) >> 16);
}
static __device__ __forceinline__ float bf2f(unsigned short h){
    return __uint_as_float(((unsigned int)h) << 16);
}

// ---------- top-2 tracking ----------
struct T2 { float v1, v2; int i1, i2; };
static __device__ __forceinline__ void t2_add(T2& t, float v, int i){
    if (v > t.v1 || (v == t.v1 && i < t.i1)) { t.v2 = t.v1; t.i2 = t.i1; t.v1 = v; t.i1 = i; }
    else if (v > t.v2 || (v == t.v2 && i < t.i2)) { t.v2 = v; t.i2 = i; }
}
static __device__ __forceinline__ T2 t2_init(){ T2 t; t.v1 = -3.4e38f; t.v2 = -3.4e38f; t.i1 = 0x7fffffff; t.i2 = 0x7fffffff; return t; }

// ---------- convert: queues fp32 -> bf16 hi/lo, fused new_queue passthrough ----------
// y==0: qtxt -> Bt_hi, Bt_lo, out3(copy).  y==1: qimg -> Bi_hi, out2(copy).
// prep_kernel runs AFTER this and overwrites out2/out3 rows 0..511 with normalized feats.
__global__ __launch_bounds__(256) void convert_kernel(
    const float* __restrict__ qtxt, const float* __restrict__ qimg,
    unsigned short* __restrict__ bthi, unsigned short* __restrict__ btlo,
    unsigned short* __restrict__ bihi,
    float* __restrict__ out3, float* __restrict__ out2)
{
    const bool isT = (blockIdx.y == 0);
    const float* __restrict__ src = isT ? qtxt : qimg;
    float* __restrict__ dst = isT ? out3 : out2;
    unsigned short* __restrict__ hi = isT ? bthi : bihi;
    unsigned short* __restrict__ lo = btlo;
    const size_t n4 = (size_t)NQ * DIM / 4;
    for (size_t i = (size_t)blockIdx.x * 256 + threadIdx.x; i < n4; i += (size_t)gridDim.x * 256) {
        f32x4 v = ((const f32x4*)src)[i];
        ((f32x4*)dst)[i] = v;
        u16x4 h, l;
        #pragma unroll
        for (int j = 0; j < 4; j++){
            unsigned short hh = f2bf(v[j]);
            h[j] = hh; l[j] = f2bf(v[j] - bf2f(hh));
        }
        *(u16x4*)(hi + 4*i) = h;
        if (isT) *(u16x4*)(lo + 4*i) = l;
    }
}

// ---------- prep: L2-normalize features, split to bf16 hi/lo, seed queue rows ----------
__global__ __launch_bounds__(256) void prep_kernel(
    const float* __restrict__ img, const float* __restrict__ txt,
    float* __restrict__ img_f, float* __restrict__ txt_f,
    unsigned short* __restrict__ X2hi, unsigned short* __restrict__ X2lo,
    unsigned short* __restrict__ X1hi, unsigned short* __restrict__ X1lo,
    float* __restrict__ out2, float* __restrict__ out3)
{
    int b = blockIdx.x;
    bool isimg = (b < BATCH);
    int row = isimg ? b : b - BATCH;
    const float* src = (isimg ? img : txt) + (size_t)row * DIM;
    float v[3];
    float ss = 0.f;
    #pragma unroll
    for (int i = 0; i < 3; i++){ v[i] = src[threadIdx.x + i*256]; ss += v[i]*v[i]; }
    #pragma unroll
    for (int m = 1; m < 64; m <<= 1) ss += __shfl_xor(ss, m);
    __shared__ float red[4];
    if ((threadIdx.x & 63) == 0) red[threadIdx.x >> 6] = ss;
    __syncthreads();
    float tot = red[0] + red[1] + red[2] + red[3];
    float scale = 1.0f / fmaxf(sqrtf(tot), 1e-12f);
    float* fdst = (isimg ? img_f : txt_f) + (size_t)row * DIM;
    float* odst = (isimg ? out2  : out3 ) + (size_t)row * DIM;
    unsigned short* hid = (isimg ? X2hi : X1hi) + (size_t)row * DIM2;
    unsigned short* lod = (isimg ? X2lo : X1lo) + (size_t)row * DIM2;
    #pragma unroll
    for (int i = 0; i < 3; i++){
        int c = threadIdx.x + i*256;
        float y = v[i] * scale;
        fdst[c] = y; odst[c] = y;
        unsigned short h = f2bf(y);
        hid[c] = h; lod[c] = f2bf(y - bf2f(h));
    }
}

// ---------- transpose W [1536][768] -> Wt [768][1536] (fp32) ----------
__global__ __launch_bounds__(256) void transpose_kernel(
    const float* __restrict__ Wd, const float* __restrict__ Wc,
    float* __restrict__ Td, float* __restrict__ Tc)
{
    __shared__ float t[32][33];
    const float* W = blockIdx.z ? Wc : Wd;
    float*       T = blockIdx.z ? Tc : Td;
    int x0 = blockIdx.x * 32;
    int y0 = blockIdx.y * 32;
    int tx = threadIdx.x & 31, ty = threadIdx.x >> 5;
    #pragma unroll
    for (int i = 0; i < 32; i += 8)
        t[ty + i][tx] = W[(size_t)(y0 + ty + i) * DIM + x0 + tx];
    __syncthreads();
    #pragma unroll
    for (int i = 0; i < 32; i += 8)
        T[(size_t)(x0 + ty + i) * DIM2 + y0 + tx] = t[tx][ty + i];
}

#define EPI_TOP2      0
#define EPI_BIAS_RELU 1
#define EPI_BIAS      2
#define EPI_SCALE     3

#define MODE_SPLIT3 0
#define MODE_K64    1

// ---------- big GEMM: C = A * B^T, both operands pre-split bf16, gload_lds staged ----------
// 256x256 tile, 8 waves (2Mx4N), per-wave 128x64. LDS rows: 128B = 8 granules of 16B,
// granule slot XOR (row&7) swizzle, staged via pre-swizzled global source (m173 pattern).
// MODE_SPLIT3: BK=32, row = [hi k0..31 | lo k0..31], 3 MFMA/frag (ah*bh + al*bh + ah*bl).
// MODE_K64:    BK=64, row = [hi k0..31 | hi k32..63] (pass Alo=Ahi+32 etc), 2 MFMA/frag.
template<int MODE, int EPI>
__global__ __launch_bounds__(512, 2) void gemm_big(
    const unsigned short* __restrict__ Ahi, const unsigned short* __restrict__ Alo, int lda,
    const unsigned short* __restrict__ Bhi, const unsigned short* __restrict__ Blo, int ldb,
    int K, int Nout,
    float* __restrict__ outp, const float* __restrict__ scale_ptr, int Mtot)
{
    constexpr int BM = 256, BN = 256, NT = 512;
    constexpr int ABYTES = BM * 128, BBYTES = BN * 128, BUF = ABYTES + BBYTES;
    constexpr int BK = (MODE == MODE_SPLIT3) ? 32 : 64;
    __shared__ __align__(16) char lds[2 * BUF];   // 128 KiB

    const int tid = threadIdx.x, lane = tid & 63, wid = tid >> 6;
    const int wm = wid >> 2, wn = wid & 3;
    const int lr = lane & 15, lg = lane >> 4;
    const int nb = blockIdx.x, mb = blockIdx.y;
    const int m0 = mb * BM, n0 = nb * BN;

    f32x4 acc[8][4] = {};

    auto stage = [&](int buf, int k0){
        char* base = lds + buf * BUF;
        #pragma unroll
        for (int r = 0; r < 4; r++){
            int G = r * NT + tid, row = G >> 3, slot = G & 7, s0 = slot ^ (row & 7);
            const unsigned short* s = ((s0 < 4) ? Ahi : Alo) + (size_t)(m0 + row) * lda + k0 + (s0 & 3) * 8;
            __builtin_amdgcn_global_load_lds(
                (const __attribute__((address_space(1))) void*)s,
                (__attribute__((address_space(3))) void*)(base + (r * NT + (tid & ~63)) * 16), 16, 0, 0);
        }
        #pragma unroll
        for (int r = 0; r < 4; r++){
            int G = r * NT + tid, row = G >> 3, slot = G & 7, s0 = slot ^ (row & 7);
            const unsigned short* s = ((s0 < 4) ? Bhi : Blo) + (size_t)(n0 + row) * ldb + k0 + (s0 & 3) * 8;
            __builtin_amdgcn_global_load_lds(
                (const __attribute__((address_space(1))) void*)s,
                (__attribute__((address_space(3))) void*)(base + ABYTES + (r * NT + (tid & ~63)) * 16), 16, 0, 0);
        }
    };

    auto compute = [&](int buf){
        const char* Ab = lds + buf * BUF;
        const char* Bb = Ab + ABYTES;
        bf16x8 bh[4], bl[4];
        #pragma unroll
        for (int nf = 0; nf < 4; nf++){
            int row = wn * 64 + nf * 16 + lr;
            const char* rp = Bb + row * 128;
            bh[nf] = *(const bf16x8*)(rp + ((lg ^ (row & 7)) << 4));
            bl[nf] = *(const bf16x8*)(rp + (((4 + lg) ^ (row & 7)) << 4));
        }
        #pragma unroll
        for (int mf = 0; mf < 8; mf++){
            int row = wm * 128 + mf * 16 + lr;
            const char* rp = Ab + row * 128;
            bf16x8 ah = *(const bf16x8*)(rp + ((lg ^ (row & 7)) << 4));
            bf16x8 al = *(const bf16x8*)(rp + (((4 + lg) ^ (row & 7)) << 4));
            #pragma unroll
            for (int nf = 0; nf < 4; nf++){
                if (MODE == MODE_SPLIT3){
                    acc[mf][nf] = __builtin_amdgcn_mfma_f32_16x16x32_bf16(ah, bh[nf], acc[mf][nf], 0, 0, 0);
                    acc[mf][nf] = __builtin_amdgcn_mfma_f32_16x16x32_bf16(al, bh[nf], acc[mf][nf], 0, 0, 0);
                    acc[mf][nf] = __builtin_amdgcn_mfma_f32_16x16x32_bf16(ah, bl[nf], acc[mf][nf], 0, 0, 0);
                } else {
                    acc[mf][nf] = __builtin_amdgcn_mfma_f32_16x16x32_bf16(ah, bh[nf], acc[mf][nf], 0, 0, 0);
                    acc[mf][nf] = __builtin_amdgcn_mfma_f32_16x16x32_bf16(al, bl[nf], acc[mf][nf], 0, 0, 0);
                }
            }
        }
    };

    stage(0, 0);
    __syncthreads();
    const int nk = K / BK;
    int cur = 0;
    for (int kt = 0; kt < nk; kt++){
        if (kt + 1 < nk) stage(cur ^ 1, (kt + 1) * BK);
        compute(cur);
        __syncthreads();
        cur ^= 1;
    }

    if constexpr (EPI == EPI_TOP2){
        T2* t2l = (T2*)lds;   // [4][256]
        #pragma unroll
        for (int mf = 0; mf < 8; mf++){
            #pragma unroll
            for (int r = 0; r < 4; r++){
                T2 t = t2_init();
                #pragma unroll
                for (int nf = 0; nf < 4; nf++){
                    int gc = n0 + wn * 64 + nf * 16 + lr;
                    t2_add(t, acc[mf][nf][r], gc);
                }
                #pragma unroll
                for (int m = 1; m < 16; m <<= 1){
                    float ov1 = __shfl_xor(t.v1, m), ov2 = __shfl_xor(t.v2, m);
                    int   oi1 = __shfl_xor(t.i1, m), oi2 = __shfl_xor(t.i2, m);
                    t2_add(t, ov1, oi1); t2_add(t, ov2, oi2);
                }
                if (lr == 0){
                    int rowit = wm * 128 + mf * 16 + lg * 4 + r;
                    t2l[wn * 256 + rowit] = t;
                }
            }
        }
        __syncthreads();
        if (tid < 256){
            T2 t = t2l[tid];
            #pragma unroll
            for (int w = 1; w < 4; w++){
                T2 o = t2l[w * 256 + tid];
                t2_add(t, o.v1, o.i1); t2_add(t, o.v2, o.i2);
            }
            f32x4 pk; pk[0] = t.v1; pk[1] = __int_as_float(t.i1); pk[2] = t.v2; pk[3] = __int_as_float(t.i2);
            ((f32x4*)outp)[(size_t)nb * Mtot + (m0 + tid)] = pk;
        }
    } else if constexpr (EPI == EPI_SCALE){
        float sc = scale_ptr[0];
        #pragma unroll
        for (int mf = 0; mf < 8; mf++)
        #pragma unroll
        for (int nf = 0; nf < 4; nf++)
        #pragma unroll
        for (int r = 0; r < 4; r++){
            int grow = m0 + wm * 128 + mf * 16 + lg * 4 + r;
            int gcol = n0 + wn * 64 + nf * 16 + lr;
            outp[(size_t)grow * Nout + gcol] = acc[mf][nf][r] * sc;
        }
    }
}

// ---------- small GEMM (MLP layers): A bf16 hi/lo, B fp32 with in-kernel convert ----------
template<int BM,int BN,int WGM,int WGN,int EPI>
__global__ __launch_bounds__(WGM*WGN*64) void gemm_small(
    const unsigned short* __restrict__ Ahi, const unsigned short* __restrict__ Alo, int lda,
    const float* __restrict__ B, int ldb, int K,
    const float* __restrict__ bias,
    unsigned short* __restrict__ dsthi, unsigned short* __restrict__ dstlo, int ldd, int dstoff)
{
    constexpr int WM = BM / WGM, WN = BN / WGN;
    constexpr int MF = WM / 16, NF = WN / 16;
    constexpr int NT = WGM * WGN * 64;
    constexpr int ABYTES = BM * 128;
    constexpr int BBYTES = BN * 128;
    constexpr int BUF = ABYTES + BBYTES;
    static_assert(BN * 4 == NT, "");
    static_assert((BM * 8) % NT == 0, "");

    __shared__ __align__(16) char lds[2 * BUF];

    const int tid  = threadIdx.x;
    const int wid  = tid >> 6, lane = tid & 63;
    const int wm   = wid / WGN, wn = wid % WGN;
    const int lr   = lane & 15, lg = lane >> 4;
    const int nb   = blockIdx.x, mb = blockIdx.y;
    const int m0   = mb * BM, n0 = nb * BN;

    f32x4 acc[MF][NF] = {};
    f32x4 breg0, breg1;

    auto stageA = [&](int buf, int k0){
        char* base = lds + buf * BUF;
        constexpr int RA = BM * 8 / NT;
        #pragma unroll
        for (int r = 0; r < RA; r++){
            int G = r * NT + tid;
            int row = G >> 3, slot = G & 7;
            int s0 = slot ^ (row & 7);
            const unsigned short* src = ((s0 < 4) ? Ahi : Alo)
                + (size_t)(m0 + row) * lda + (k0 + (s0 & 3) * 8);
            char* ldst = base + r * NT * 16 + (tid & ~63) * 16;
            __builtin_amdgcn_global_load_lds(
                (const __attribute__((address_space(1))) void*)src,
                (__attribute__((address_space(3))) void*)ldst, 16, 0, 0);
        }
    };
    auto loadB = [&](int kt){
        int k0 = kt * 32;
        int row = tid >> 2, quad = tid & 3;
        const float* bp = B + (size_t)(n0 + row) * ldb + k0 + quad * 8;
        breg0 = *(const f32x4*)bp;
        breg1 = *(const f32x4*)(bp + 4);
    };
    auto writeB = [&](int buf){
        char* base = lds + buf * BUF + ABYTES;
        int row = tid >> 2, quad = tid & 3;
        u16x8 h8, l8;
        #pragma unroll
        for (int j = 0; j < 8; j++){
            float x = (j < 4) ? breg0[j] : breg1[j - 4];
            unsigned short h = f2bf(x);
            h8[j] = h; l8[j] = f2bf(x - bf2f(h));
        }
        int sh = quad ^ (row & 7), sl = (4 + quad) ^ (row & 7);
        *(u16x8*)(base + row * 128 + sh * 16) = h8;
        *(u16x8*)(base + row * 128 + sl * 16) = l8;
    };
    auto compute = [&](int buf){
        const char* Ab = lds + buf * BUF;
        const char* Bb = Ab + ABYTES;
        bf16x8 ah[MF], al[MF], bh[NF], bl[NF];
        #pragma unroll
        for (int mf = 0; mf < MF; mf++){
            int row = wm * WM + mf * 16 + lr;
            const char* rp = Ab + row * 128;
            ah[mf] = *(const bf16x8*)(rp + ((lg ^ (row & 7)) << 4));
            al[mf] = *(const bf16x8*)(rp + (((4 + lg) ^ (row & 7)) << 4));
        }
        #pragma unroll
        for (int nf = 0; nf < NF; nf++){
            int row = wn * WN + nf * 16 + lr;
            const char* rp = Bb + row * 128;
            bh[nf] = *(const bf16x8*)(rp + ((lg ^ (row & 7)) << 4));
            bl[nf] = *(const bf16x8*)(rp + (((4 + lg) ^ (row & 7)) << 4));
        }
        #pragma unroll
        for (int mf = 0; mf < MF; mf++)
        #pragma unroll
        for (int nf = 0; nf < NF; nf++){
            acc[mf][nf] = __builtin_amdgcn_mfma_f32_16x16x32_bf16(ah[mf], bh[nf], acc[mf][nf], 0, 0, 0);
            acc[mf][nf] = __builtin_amdgcn_mfma_f32_16x16x32_bf16(al[mf], bh[nf], acc[mf][nf], 0, 0, 0);
            acc[mf][nf] = __builtin_amdgcn_mfma_f32_16x16x32_bf16(ah[mf], bl[nf], acc[mf][nf], 0, 0, 0);
        }
    };

    stageA(0, 0); loadB(0); writeB(0);
    __syncthreads();
    const int nk = K / 32;
    int cur = 0;
    for (int kt = 0; kt < nk; kt++){
        if (kt + 1 < nk){ stageA(cur ^ 1, (kt + 1) * 32); loadB(kt + 1); }
        compute(cur);
        if (kt + 1 < nk){ writeB(cur ^ 1); }
        __syncthreads();
        cur ^= 1;
    }

    #pragma unroll
    for (int mf = 0; mf < MF; mf++)
    #pragma unroll
    for (int nf = 0; nf < NF; nf++)
    #pragma unroll
    for (int r = 0; r < 4; r++){
        int grow = m0 + wm * WM + mf * 16 + lg * 4 + r;
        int gcol = n0 + wn * WN + nf * 16 + lr;
        float c = acc[mf][nf][r] + bias[gcol];
        if (EPI == EPI_BIAS_RELU) c = fmaxf(c, 0.f);
        unsigned short h = f2bf(c);
        size_t o = (size_t)grow * ldd + dstoff + gcol;
        dsthi[o] = h;
        dstlo[o] = f2bf(c - bf2f(h));
    }
}

// ---------- phase B: global top-2 merge + exact fp32 rescore -> argmax index ----------
__global__ __launch_bounds__(64) void phaseB_kernel(
    const f32x4* __restrict__ top2ws, int ntiles,
    const float* __restrict__ img_f, const float* __restrict__ qtxt,
    float* __restrict__ out_ind, int* __restrict__ ws_ind)
{
    int row = blockIdx.x;
    int lane = threadIdx.x;
    T2 t = t2_init();
    for (int j = lane; j < ntiles; j += 64){
        f32x4 e = top2ws[(size_t)j * BATCH + row];
        t2_add(t, e[0], __float_as_int(e[1]));
        t2_add(t, e[2], __float_as_int(e[3]));
    }
    #pragma unroll
    for (int m = 1; m < 64; m <<= 1){
        float ov1 = __shfl_xor(t.v1, m), ov2 = __shfl_xor(t.v2, m);
        int   oi1 = __shfl_xor(t.i1, m), oi2 = __shfl_xor(t.i2, m);
        t2_add(t, ov1, oi1); t2_add(t, ov2, oi2);
    }
    const float* a  = img_f + (size_t)row * DIM;
    const float* b1 = qtxt + (size_t)t.i1 * DIM;
    const float* b2 = qtxt + (size_t)t.i2 * DIM;
    float s1 = 0.f, s2 = 0.f;
    for (int c = lane; c < DIM; c += 64){ float av = a[c]; s1 += av * b1[c]; s2 += av * b2[c]; }
    #pragma unroll
    for (int m = 1; m < 64; m <<= 1){ s1 += __shfl_xor(s1, m); s2 += __shfl_xor(s2, m); }
    int ind = (s2 > s1 || (s2 == s1 && t.i2 < t.i1)) ? t.i2 : t.i1;
    if (lane == 0){ out_ind[row] = (float)ind; ws_ind[row] = ind; }
}

// ---------- gather t_similar rows into X1[:, 768:1536] as bf16 hi/lo ----------
__global__ __launch_bounds__(256) void gather_kernel(
    const int* __restrict__ ws_ind, const float* __restrict__ qtxt,
    unsigned short* __restrict__ X1hi, unsigned short* __restrict__ X1lo)
{
    int row = blockIdx.x;
    int ind = ws_ind[row];
    const float* src = qtxt + (size_t)ind * DIM;
    for (int c = threadIdx.x; c < DIM; c += 256){
        float x = src[c];
        unsigned short h = f2bf(x);
        X1hi[(size_t)row * DIM2 + DIM + c] = h;
        X1lo[(size_t)row * DIM2 + DIM + c] = f2bf(x - bf2f(h));
    }
}

extern "C" void kernel_launch(void* const* d_in, const int* in_sizes, int n_in,
                              void* d_out, int out_size, void* d_ws, size_t ws_size,
                              hipStream_t stream)
{
    (void)in_sizes; (void)n_in; (void)out_size; (void)ws_size;
    const float* img  = (const float*)d_in[0];
    const float* txt  = (const float*)d_in[1];
    const float* qimg = (const float*)d_in[2];
    const float* qtxt = (const float*)d_in[3];
    const float* Wd   = (const float*)d_in[4];
    const float* bd   = (const float*)d_in[5];
    const float* Wc   = (const float*)d_in[6];
    const float* bc   = (const float*)d_in[7];
    const float* ls   = (const float*)d_in[8];

    float* out0 = (float*)d_out;                    // logits [512][65536]
    float* out1 = out0 + (size_t)BATCH * NQ;        // ind_similar [512] (as f32)
    float* out2 = out1 + BATCH;                     // new_queue_img [65536][768]
    float* out3 = out2 + (size_t)NQ * DIM;          // new_queue_txt [65536][768]

    char* w = (char*)d_ws;
    auto alloc = [&](size_t bytes){ char* p = w; w += (bytes + 255) & ~(size_t)255; return p; };
    unsigned short* X1hi  = (unsigned short*)alloc((size_t)BATCH * DIM2 * 2);
    unsigned short* X1lo  = (unsigned short*)alloc((size_t)BATCH * DIM2 * 2);
    unsigned short* X2hi  = (unsigned short*)alloc((size_t)BATCH * DIM2 * 2);
    unsigned short* X2lo  = (unsigned short*)alloc((size_t)BATCH * DIM2 * 2);
    unsigned short* combhi= (unsigned short*)alloc((size_t)BATCH * DIM * 2);
    unsigned short* comblo= (unsigned short*)alloc((size_t)BATCH * DIM * 2);
    float* img_f  = (float*)alloc((size_t)BATCH * DIM * 4);
    float* txt_f  = (float*)alloc((size_t)BATCH * DIM * 4);
    float* Td     = (float*)alloc((size_t)DIM * DIM2 * 4);
    float* Tc     = (float*)alloc((size_t)DIM * DIM2 * 4);
    float* top2ws = (float*)alloc((size_t)(NQ / 256) * BATCH * 16);
    int*   ws_ind = (int*)alloc(BATCH * 4);
    unsigned short* Bt_hi = (unsigned short*)alloc((size_t)NQ * DIM * 2);
    unsigned short* Bt_lo = (unsigned short*)alloc((size_t)NQ * DIM * 2);
    unsigned short* Bi_hi = (unsigned short*)alloc((size_t)NQ * DIM * 2);

    // 1) convert queues to bf16 hi/lo + full fp32 passthrough into out2/out3
    convert_kernel<<<dim3(2048, 2), dim3(256), 0, stream>>>(
        qtxt, qimg, Bt_hi, Bt_lo, Bi_hi, out3, out2);

    // 2) normalize features (overwrites out2/out3 rows 0..511), split to hi/lo
    prep_kernel<<<dim3(2 * BATCH), dim3(256), 0, stream>>>(
        img, txt, img_f, txt_f, X2hi, X2lo, X1hi, X1lo, out2, out3);

    // 3) transpose weights to [768][1536] fp32
    transpose_kernel<<<dim3(DIM / 32, DIM2 / 32, 2), dim3(256), 0, stream>>>(Wd, Wc, Td, Tc);

    // 4) retrieval GEMM (split-bf16, 3 terms) + per-tile top2
    gemm_big<MODE_SPLIT3, EPI_TOP2><<<dim3(NQ / 256, 2), dim3(512), 0, stream>>>(
        X2hi, X2lo, DIM2, Bt_hi, Bt_lo, DIM, DIM, NQ, top2ws, nullptr, BATCH);

    // 5) global top-2 + exact rescore -> ind_similar
    phaseB_kernel<<<dim3(BATCH), dim3(64), 0, stream>>>(
        (const f32x4*)top2ws, NQ / 256, img_f, qtxt, out1, ws_ind);

    // 6) gather t_similar into X1[:, 768:]
    gather_kernel<<<dim3(BATCH), dim3(256), 0, stream>>>(ws_ind, qtxt, X1hi, X1lo);

    // 7) diff = relu(X1 @ W_diff + b_diff) -> X2[:, 768:] (split)
    gemm_small<64,64,2,2,EPI_BIAS_RELU><<<dim3(DIM / 64, BATCH / 64), dim3(256), 0, stream>>>(
        X1hi, X1lo, DIM2, Td, DIM2, DIM2, bd, X2hi, X2lo, DIM2, DIM);

    // 8) combined = X2 @ W_comb + b_comb -> comb hi/lo
    gemm_small<64,64,2,2,EPI_BIAS><<<dim3(DIM / 64, BATCH / 64), dim3(256), 0, stream>>>(
        X2hi, X2lo, DIM2, Tc, DIM2, DIM2, bc, combhi, comblo, DIM, 0);

    // 9) logits = scale * combined @ queue_img^T   (K64 hi-only mode: lo = hi + 32)
    gemm_big<MODE_K64, EPI_SCALE><<<dim3(NQ / 256, 2), dim3(512), 0, stream>>>(
        combhi, combhi + 32, DIM, Bi_hi, Bi_hi + 32, DIM, DIM, NQ, out0, ls, BATCH);
}